// Round 1
// baseline (1351.429 us; speedup 1.0000x reference)
//
#include <hip/hip_runtime.h>
#include <stdint.h>
#include <stddef.h>

// Problem constants (fixed by reference setup_inputs)
#define BATCH 4096
#define HID   1024
#define EMB   64
#define KDIM  1088   // EMB + HID
#define NSTEP 19     // (SEQ-1) + (n_predict-1) = 8 + 11
#define NOBS  8

typedef _Float16 f16;
typedef _Float16 half8 __attribute__((ext_vector_type(8)));
typedef _Float16 half4v __attribute__((ext_vector_type(4)));
typedef float    float4v __attribute__((ext_vector_type(4)));

// ---------------------------------------------------------------------------
// helpers
// ---------------------------------------------------------------------------
__device__ __forceinline__ float sigm(float x) { return 1.f / (1.f + __expf(-x)); }
// NaN-free tanh: saturates to +-1 cleanly
__device__ __forceinline__ float tanh_f(float x) { return 1.f - 2.f / (__expf(2.f * x) + 1.f); }

__device__ __forceinline__ void gload_lds16(const void* gp, void* lp) {
  __builtin_amdgcn_global_load_lds(
      (const __attribute__((address_space(1))) uint32_t*)gp,
      (__attribute__((address_space(3))) uint32_t*)lp, 16, 0, 0);
}

// ---------------------------------------------------------------------------
// Pack W_ih|W_hh (fp32) into interleaved fp16 Wc [4096][1088] + combined bias.
// Packed row p = 128*t + 32*g + u  <->  original gate row g*1024 + 32*t + u.
// So a 128-wide N-tile t holds gates i,f,g,o for j in [32t, 32t+32).
// ---------------------------------------------------------------------------
__global__ void pack_kernel(const float* __restrict__ W_ih, const float* __restrict__ b_ih,
                            const float* __restrict__ W_hh, const float* __restrict__ b_hh,
                            f16* __restrict__ Wc, float* __restrict__ bc) {
  int gid = blockIdx.x * blockDim.x + threadIdx.x;  // over 4096*1088
  int p = gid / KDIM;
  int k = gid - p * KDIM;
  int t = p >> 7;
  int g = (p >> 5) & 3;
  int u = p & 31;
  int orig = g * HID + t * 32 + u;
  float v = (k < EMB) ? W_ih[orig * EMB + k] : W_hh[orig * HID + (k - EMB)];
  Wc[gid] = (f16)v;
  if (k == 0) bc[p] = b_ih[orig] + b_hh[orig];
}

// ---------------------------------------------------------------------------
// Embedding: X[b][0:64] = fp16(relu(d @ W_emb^T + b_emb))
// obs mode: d = src1[b] - src0[b] (stride 2); pred mode: d = src1[b*5 + 0:2]
// ---------------------------------------------------------------------------
__global__ void emb_kernel(const float* __restrict__ src0, const float* __restrict__ src1,
                           int src_stride, int do_sub,
                           const float* __restrict__ W_emb, const float* __restrict__ b_emb,
                           f16* __restrict__ Xc) {
  int gid = blockIdx.x * blockDim.x + threadIdx.x;  // BATCH*EMB
  int b = gid >> 6, j = gid & 63;
  float d0 = src1[b * src_stride];
  float d1 = src1[b * src_stride + 1];
  if (do_sub) {
    d0 -= src0[b * src_stride];
    d1 -= src0[b * src_stride + 1];
  }
  float v = d0 * W_emb[2 * j] + d1 * W_emb[2 * j + 1] + b_emb[j];
  Xc[(size_t)b * KDIM + j] = (f16)fmaxf(v, 0.f);
}

// ---------------------------------------------------------------------------
// Fused gates-GEMM + LSTM cell.
// C[128 b][128 packed-gates] per block; wave w owns b-rows [w*32, w*32+32),
// all 128 N cols -> acc[2][8] (16 MFMA tiles). Because of the packed row
// order, lane (l&15) at register r holds the i/f/g/o quadruple for one (b,j)
// in acc[mi][u16 + 2*gate][r] -> cell epilogue is fully in-register.
// ---------------------------------------------------------------------------
#define BM 128
#define BN 128
#define BK 32

__global__ __launch_bounds__(256, 2)
void gemm_cell_kernel(const f16* __restrict__ Xc, const f16* __restrict__ Wc,
                      const float* __restrict__ bc,
                      float* __restrict__ c_st, f16* __restrict__ Xn) {
  __shared__ f16 smem[2 * BM * BK];  // [0,4096): A tile, [4096,8192): B tile (halves)
  const int tid = threadIdx.x;
  const int lane = tid & 63;
  const int w = tid >> 6;
  const int l15 = lane & 15;
  const int quad = lane >> 4;
  const int bm = blockIdx.y, bn = blockIdx.x;

  float4v acc[2][8];
#pragma unroll
  for (int mi = 0; mi < 2; ++mi)
#pragma unroll
    for (int ni = 0; ni < 8; ++ni)
      acc[mi][ni] = (float4v){0.f, 0.f, 0.f, 0.f};

  for (int kt = 0; kt < KDIM / BK; ++kt) {
    const int k0 = kt * BK;
    __syncthreads();
    // stage A (X rows) and B (Wc rows), 16B per lane, XOR-swizzled chunks:
    // LDS slot s=(r,cp) holds global chunk cl = cp ^ ((r>>1)&3)
#pragma unroll
    for (int cph = 0; cph < 2; ++cph) {
      int s = tid + cph * 256;
      int r = s >> 2;
      int cl = (s & 3) ^ ((r >> 1) & 3);
      const f16* ga = Xc + (size_t)(bm * BM + r) * KDIM + k0 + cl * 8;
      const f16* gb = Wc + (size_t)(bn * BN + r) * KDIM + k0 + cl * 8;
      uint32_t lbase = (uint32_t)(w * 64 + cph * 256) * 16;  // wave-uniform; HW adds lane*16
      gload_lds16(ga, (char*)smem + lbase);
      gload_lds16(gb, (char*)smem + 8192 + lbase);
    }
    __syncthreads();

    half8 afrag[2], bfrag[8];
#pragma unroll
    for (int mi = 0; mi < 2; ++mi) {
      int r = w * 32 + mi * 16 + l15;
      int cp = quad ^ ((r >> 1) & 3);
      afrag[mi] = *(const half8*)(smem + r * 32 + cp * 8);
    }
#pragma unroll
    for (int ni = 0; ni < 8; ++ni) {
      int r = ni * 16 + l15;
      int cp = quad ^ ((r >> 1) & 3);
      bfrag[ni] = *(const half8*)(smem + BM * BK + r * 32 + cp * 8);
    }
#pragma unroll
    for (int mi = 0; mi < 2; ++mi)
#pragma unroll
      for (int ni = 0; ni < 8; ++ni)
        acc[mi][ni] = __builtin_amdgcn_mfma_f32_16x16x32_f16(afrag[mi], bfrag[ni], acc[mi][ni], 0, 0, 0);
  }

  // ---- in-register LSTM cell epilogue ----
  float bias[8];
#pragma unroll
  for (int ni = 0; ni < 8; ++ni) bias[ni] = bc[bn * BN + ni * 16 + l15];

#pragma unroll
  for (int mi = 0; mi < 2; ++mi) {
#pragma unroll
    for (int u16 = 0; u16 < 2; ++u16) {
      const int j = bn * 32 + u16 * 16 + l15;
#pragma unroll
      for (int r = 0; r < 4; ++r) {
        const int brow = bm * BM + w * 32 + mi * 16 + quad * 4 + r;
        float gi = acc[mi][u16 + 0][r] + bias[u16 + 0];
        float gf = acc[mi][u16 + 2][r] + bias[u16 + 2];
        float gg = acc[mi][u16 + 4][r] + bias[u16 + 4];
        float go = acc[mi][u16 + 6][r] + bias[u16 + 6];
        size_t cix = (size_t)brow * HID + j;
        float co = c_st[cix];
        float cn = sigm(gf) * co + sigm(gi) * tanh_f(gg);
        c_st[cix] = cn;
        float h = sigm(go) * tanh_f(cn);
        Xn[(size_t)brow * KDIM + EMB + j] = (f16)h;
      }
    }
  }
}

// ---------------------------------------------------------------------------
// Output projection: out[b][0:5] = h[b] @ W_out^T + b_out  (h read as fp16)
// one block per batch row
// ---------------------------------------------------------------------------
__global__ void out_kernel(const f16* __restrict__ Xn, const float* __restrict__ W_out,
                           const float* __restrict__ b_out, float* __restrict__ out) {
  const int b = blockIdx.x;
  const int tid = threadIdx.x;
  const int k = tid * 4;  // 256 threads * 4 = 1024
  float acc[5];
  half4v h4 = *(const half4v*)(Xn + (size_t)b * KDIM + EMB + k);
  float h0 = (float)h4[0], h1 = (float)h4[1], h2 = (float)h4[2], h3 = (float)h4[3];
#pragma unroll
  for (int o = 0; o < 5; ++o) {
    float4v wv = *(const float4v*)(W_out + o * HID + k);
    acc[o] = h0 * wv[0] + h1 * wv[1] + h2 * wv[2] + h3 * wv[3];
  }
#pragma unroll
  for (int s = 32; s > 0; s >>= 1)
#pragma unroll
    for (int o = 0; o < 5; ++o) acc[o] += __shfl_down(acc[o], s, 64);

  __shared__ float red[4][5];
  const int wv_ = tid >> 6, lane = tid & 63;
  if (lane == 0)
#pragma unroll
    for (int o = 0; o < 5; ++o) red[wv_][o] = acc[o];
  __syncthreads();
  if (tid < 5) {
    float v = red[0][tid] + red[1][tid] + red[2][tid] + red[3][tid] + b_out[tid];
    out[(size_t)b * 5 + tid] = v;
  }
}

// ---------------------------------------------------------------------------
extern "C" void kernel_launch(void* const* d_in, const int* in_sizes, int n_in,
                              void* d_out, int out_size, void* d_ws, size_t ws_size,
                              hipStream_t stream) {
  const float* observed = (const float*)d_in[0];
  const float* W_emb = (const float*)d_in[1];
  const float* b_emb = (const float*)d_in[2];
  const float* W_ih = (const float*)d_in[3];
  const float* b_ih = (const float*)d_in[4];
  const float* W_hh = (const float*)d_in[5];
  const float* b_hh = (const float*)d_in[6];
  const float* W_out = (const float*)d_in[7];
  const float* b_out = (const float*)d_in[8];
  float* out = (float*)d_out;

  uint8_t* ws = (uint8_t*)d_ws;
  const size_t WC_BYTES = (size_t)4096 * KDIM * 2;  // 8,912,896
  f16* Wc = (f16*)ws;
  float* bc = (float*)(ws + WC_BYTES);
  f16* X0 = (f16*)(ws + WC_BYTES + 16384);
  f16* X1 = (f16*)(ws + 2 * WC_BYTES + 16384);
  float* cst = (float*)(ws + 3 * WC_BYTES + 16384);

  pack_kernel<<<(4096 * KDIM) / 256, 256, 0, stream>>>(W_ih, b_ih, W_hh, b_hh, Wc, bc);
  hipMemsetAsync(X0, 0, WC_BYTES, stream);                       // h0 = 0
  hipMemsetAsync(cst, 0, (size_t)BATCH * HID * 4, stream);       // c0 = 0

  f16* Xc = X0;
  f16* Xn = X1;
  for (int t = 0; t < NSTEP; ++t) {
    if (t < NOBS) {
      emb_kernel<<<(BATCH * EMB) / 256, 256, 0, stream>>>(
          observed + (size_t)t * BATCH * 2, observed + (size_t)(t + 1) * BATCH * 2,
          2, 1, W_emb, b_emb, Xc);
    } else {
      emb_kernel<<<(BATCH * EMB) / 256, 256, 0, stream>>>(
          nullptr, out + (size_t)(t - 1) * BATCH * 5, 5, 0, W_emb, b_emb, Xc);
    }
    dim3 grid(BATCH / BN, BATCH / BM);
    gemm_cell_kernel<<<grid, 256, 0, stream>>>(Xc, Wc, bc, cst, Xn);
    out_kernel<<<BATCH, 256, 0, stream>>>(Xn, W_out, b_out, out + (size_t)t * BATCH * 5);
    f16* tmp = Xc; Xc = Xn; Xn = tmp;
  }
}